// Round 1
// baseline (206.665 us; speedup 1.0000x reference)
//
#include <hip/hip_runtime.h>

// ---------- small helpers ----------
typedef __attribute__((ext_vector_type(8))) short bf16x8;
typedef __attribute__((ext_vector_type(4))) float f32x4;

typedef const __attribute__((address_space(1))) void* as1cv;
typedef __attribute__((address_space(3))) void* as3v;

__device__ __forceinline__ unsigned short f2bf(float f) {
    union { float f; unsigned u; } x; x.f = f;
    unsigned r = x.u + 0x7FFFu + ((x.u >> 16) & 1u);   // RNE
    return (unsigned short)(r >> 16);
}
__device__ __forceinline__ float bf2f(unsigned short u) {
    union { unsigned u; float f; } x; x.u = ((unsigned)u) << 16; return x.f;
}

// ---------- 1. fp32 -> bf16 convert (vectorized, grid-stride) ----------
__global__ void k_cvt_bf16(const float* __restrict__ in, unsigned short* __restrict__ out, long n) {
    long i = (long)blockIdx.x * blockDim.x + threadIdx.x;
    long stride = (long)gridDim.x * blockDim.x;
    long n4 = n >> 2;
    for (long j = i; j < n4; j += stride) {
        float4 v = ((const float4*)in)[j];
        ushort4 o;
        o.x = f2bf(v.x); o.y = f2bf(v.y); o.z = f2bf(v.z); o.w = f2bf(v.w);
        ((ushort4*)out)[j] = o;
    }
}

// ---------- 2. W (rows x cols, f32) -> Wt (cols x rows, bf16) ----------
__global__ void k_transpose_bf16(const float* __restrict__ W, unsigned short* __restrict__ Wt,
                                 int rows, int cols) {
    __shared__ float tile[64][65];
    int r0 = blockIdx.y * 64, c0 = blockIdx.x * 64;
    #pragma unroll
    for (int i = 0; i < 16; ++i) {
        int idx = threadIdx.x + i * 256;
        int r = idx >> 6, c = idx & 63;
        tile[r][c] = W[(long)(r0 + r) * cols + (c0 + c)];
    }
    __syncthreads();
    #pragma unroll
    for (int i = 0; i < 16; ++i) {
        int idx = threadIdx.x + i * 256;
        int r = idx >> 6, c = idx & 63;
        Wt[(long)(c0 + r) * rows + (r0 + c)] = f2bf(tile[c][r]);
    }
}

// ---------- 3. GEMM: C(MxN) = A(MxK) * Bt(NxK)^T + bias ----------
// 128x128 tile, BK=32, 256 threads (4 waves, 2x2), wave tile 64x64, mfma 16x16x32 bf16
template<int OUT_BF16>
__global__ __launch_bounds__(256, 2) void k_gemm_bt(
    const unsigned short* __restrict__ A,
    const unsigned short* __restrict__ Bt,
    const float* __restrict__ bias,
    void* __restrict__ C,
    int M, int N, int K)
{
    __shared__ unsigned short As[128 * 32];
    __shared__ unsigned short Bs[128 * 32];
    const int tid = threadIdx.x;
    const int nblks = N >> 7;
    const int mblk = blockIdx.x / nblks;
    const int nblk = blockIdx.x - mblk * nblks;
    const long m0 = (long)mblk << 7;
    const long n0 = (long)nblk << 7;
    const int lane = tid & 63, wave = tid >> 6;
    const int wr = wave >> 1, wc = wave & 1;

    // staging: chunk c covers LDS bytes [c*16, c*16+16) = row c/4, col-bytes (c%4)*16
    const int c0 = tid, c1 = tid + 256;
    const unsigned short* Ag0 = A + ((long)(m0 + (c0 >> 2))) * K + ((c0 & 3) << 3);
    const unsigned short* Ag1 = A + ((long)(m0 + (c1 >> 2))) * K + ((c1 & 3) << 3);
    const unsigned short* Bg0 = Bt + ((long)(n0 + (c0 >> 2))) * K + ((c0 & 3) << 3);
    const unsigned short* Bg1 = Bt + ((long)(n0 + (c1 >> 2))) * K + ((c1 & 3) << 3);

    f32x4 acc[4][4];
    #pragma unroll
    for (int i = 0; i < 4; ++i)
        #pragma unroll
        for (int j = 0; j < 4; ++j)
            acc[i][j] = (f32x4){0.f, 0.f, 0.f, 0.f};

    const int kq = lane >> 4, rr = lane & 15;
    const unsigned short* Ap = As + (((wr << 6) + rr) << 5) + (kq << 3);
    const unsigned short* Bp = Bs + (((wc << 6) + rr) << 5) + (kq << 3);

    for (int k0 = 0; k0 < K; k0 += 32) {
        __builtin_amdgcn_global_load_lds((as1cv)(Ag0 + k0), (as3v)(As + c0 * 8), 16, 0, 0);
        __builtin_amdgcn_global_load_lds((as1cv)(Ag1 + k0), (as3v)(As + c1 * 8), 16, 0, 0);
        __builtin_amdgcn_global_load_lds((as1cv)(Bg0 + k0), (as3v)(Bs + c0 * 8), 16, 0, 0);
        __builtin_amdgcn_global_load_lds((as1cv)(Bg1 + k0), (as3v)(Bs + c1 * 8), 16, 0, 0);
        asm volatile("s_waitcnt vmcnt(0)" ::: "memory");
        __syncthreads();

        bf16x8 af[4], bfr[4];
        #pragma unroll
        for (int i = 0; i < 4; ++i) {
            af[i]  = *(const bf16x8*)(Ap + (i << 9));   // +16 rows = +512 elems
            bfr[i] = *(const bf16x8*)(Bp + (i << 9));
        }
        #pragma unroll
        for (int i = 0; i < 4; ++i)
            #pragma unroll
            for (int j = 0; j < 4; ++j)
                acc[i][j] = __builtin_amdgcn_mfma_f32_16x16x32_bf16(af[i], bfr[j], acc[i][j], 0, 0, 0);
        __syncthreads();
    }

    // epilogue: C/D layout col = lane&15, row = (lane>>4)*4 + reg
    const long rowb = m0 + (wr << 6) + (kq << 2);
    const long colb = n0 + (wc << 6) + rr;
    #pragma unroll
    for (int nj = 0; nj < 4; ++nj) {
        const long col = colb + nj * 16;
        const float bv = bias[col];
        #pragma unroll
        for (int mi = 0; mi < 4; ++mi) {
            #pragma unroll
            for (int jj = 0; jj < 4; ++jj) {
                const long row = rowb + mi * 16 + jj;
                float v = acc[mi][nj][jj] + bv;
                if (OUT_BF16) ((unsigned short*)C)[row * N + col] = f2bf(v);
                else          ((float*)C)[row * N + col] = v;
            }
        }
    }
}

// ---------- 4. column sums: total[b][d] = sum_t p[b,t,d] ----------
__global__ void k_colsum(const unsigned short* __restrict__ p, float* __restrict__ total, int T) {
    const int b = blockIdx.y;
    const int t0 = blockIdx.x * 64;
    const int tid = threadIdx.x;
    float s0 = 0.f, s1 = 0.f, s2 = 0.f, s3 = 0.f;
    const unsigned short* base = p + ((long)b * T + t0) * 1024 + tid * 4;
    for (int t = 0; t < 64; ++t) {
        ushort4 v = *(const ushort4*)(base + (long)t * 1024);
        s0 += bf2f(v.x); s1 += bf2f(v.y); s2 += bf2f(v.z); s3 += bf2f(v.w);
    }
    float* tp = total + b * 1024 + tid * 4;
    atomicAdd(tp + 0, s0); atomicAdd(tp + 1, s1);
    atomicAdd(tp + 2, s2); atomicAdd(tp + 3, s3);
}

// ---------- 5. FSMN: band FIR + mw0*(total - windowsum) ----------
// block: 64 d's x 32 t's; thread: 1 d, 8 t's. LDS window in fp32.
__global__ __launch_bounds__(256) void k_fsmn(
    const unsigned short* __restrict__ p,   // (B*T, 1024) bf16
    const float* __restrict__ mw,           // (41, 1024) fp32
    const float* __restrict__ total,        // (B, 1024) fp32
    unsigned short* __restrict__ p2,        // (B*T, 1024) bf16
    int T)
{
    __shared__ float sp[71 * 64];
    __shared__ float smw[41 * 64];
    const int b  = blockIdx.z;
    const int t0 = blockIdx.y * 32;
    const int d0 = blockIdx.x * 64;
    const int tid = threadIdx.x;

    for (int idx = tid; idx < 41 * 64; idx += 256) {
        int r = idx >> 6, c = idx & 63;
        smw[idx] = mw[r * 1024 + d0 + c];
    }
    for (int idx = tid; idx < 71 * 64; idx += 256) {
        int r = idx >> 6, c = idx & 63;
        int t = t0 + r - 39;
        float v = 0.f;
        if (t >= 0) v = bf2f(p[((long)b * T + t) * 1024 + d0 + c]);
        sp[idx] = v;
    }
    __syncthreads();

    const int d_l = tid & 63, tg = tid >> 6;
    float w[47];
    #pragma unroll
    for (int j = 0; j < 47; ++j) w[j] = sp[(tg * 8 + j) * 64 + d_l];  // w[j] = p[t0+tg*8+j-39]

    float accb[8] = {0,0,0,0,0,0,0,0};
    float accw[8] = {0,0,0,0,0,0,0,0};
    #pragma unroll
    for (int lag = 0; lag < 40; ++lag) {
        const float m = smw[(1 + lag) * 64 + d_l];
        #pragma unroll
        for (int t = 0; t < 8; ++t) {
            const float v = w[t + 39 - lag];
            accb[t] += m * v;
            accw[t] += v;
        }
    }
    const float m0v = smw[d_l];
    const float tot = total[b * 1024 + d0 + d_l];
    #pragma unroll
    for (int t = 0; t < 8; ++t) {
        float outv = accb[t] + m0v * (tot - accw[t]);
        p2[((long)b * T + t0 + tg * 8 + t) * 1024 + d0 + d_l] = f2bf(outv);
    }
}

// ---------- launch ----------
extern "C" void kernel_launch(void* const* d_in, const int* in_sizes, int n_in,
                              void* d_out, int out_size, void* d_ws, size_t ws_size,
                              hipStream_t stream) {
    const float* x  = (const float*)d_in[0];
    const float* W1 = (const float*)d_in[1];
    const float* b1 = (const float*)d_in[2];
    const float* W2 = (const float*)d_in[3];
    const float* b2 = (const float*)d_in[4];
    const float* mw = (const float*)d_in[5];
    float* out = (float*)d_out;

    const int B = 8, T = 2048;
    const long M = (long)B * T;          // 16384 rows
    const int N = 1024, K = 1024;

    // ws layout (needs ~68 MB):
    // [0, 32MB)        x_bf   (reused as p2_bf after GEMM1 consumed x_bf)
    // [32MB, 34MB)     W1t
    // [34MB, 36MB)     W2t
    // [36MB, 68MB)     p_bf
    // [68MB, +32KB)    totals
    char* ws = (char*)d_ws;
    unsigned short* x_bf   = (unsigned short*)(ws);
    unsigned short* W1t    = (unsigned short*)(ws + 33554432L);
    unsigned short* W2t    = (unsigned short*)(ws + 35651584L);
    unsigned short* p_bf   = (unsigned short*)(ws + 37748736L);
    float*          totals = (float*)(ws + 71303168L);
    unsigned short* p2_bf  = x_bf;

    k_cvt_bf16<<<2048, 256, 0, stream>>>(x, x_bf, M * 1024);

    dim3 tgrid(16, 16);
    k_transpose_bf16<<<tgrid, 256, 0, stream>>>(W1, W1t, K, N);
    k_transpose_bf16<<<tgrid, 256, 0, stream>>>(W2, W2t, K, N);

    k_gemm_bt<1><<<dim3((int)((M / 128) * (N / 128))), 256, 0, stream>>>(
        x_bf, W1t, b1, (void*)p_bf, (int)M, N, K);

    hipMemsetAsync(totals, 0, B * 1024 * sizeof(float), stream);
    k_colsum<<<dim3(T / 64, B), 256, 0, stream>>>(p_bf, totals, T);

    k_fsmn<<<dim3(1024 / 64, T / 32, B), 256, 0, stream>>>(p_bf, mw, totals, p2_bf, T);

    k_gemm_bt<0><<<dim3((int)((M / 128) * (N / 128))), 256, 0, stream>>>(
        p2_bf, W2t, b2, (void*)out, (int)M, N, K);
}